// Round 8
// baseline (87.730 us; speedup 1.0000x reference)
//
#include <hip/hip_runtime.h>

#define NN 128
#define DD 768
#define TT 16
#define PP 196
#define SCL 0.03608439182435161f  // 1/sqrt(768)
#define VS 776                    // Vl row stride (ushorts): 16B-aligned, bank-skewed

typedef short short8 __attribute__((ext_vector_type(8)));
typedef float f32x4 __attribute__((ext_vector_type(4)));

static __device__ __forceinline__ ushort f2bf(float f) {
    union { float f; unsigned int u; } a; a.f = f;
    unsigned int r = a.u + 0x7fffu + ((a.u >> 16) & 1u);
    return (ushort)(r >> 16);
}

// ---------------- K0: LayerNorm of the 128 cls rows -> qn bf16 ----------------
__global__ __launch_bounds__(256) void k_lnq(const float* __restrict__ x,
                                             const float* __restrict__ gamma,
                                             const float* __restrict__ beta,
                                             ushort* __restrict__ qn) {
    int row  = (blockIdx.x << 2) + (threadIdx.x >> 6);   // 0..127
    int lane = threadIdx.x & 63;
    const float4* xr = (const float4*)(x + (size_t)row * DD);
    float4 v[3];
    float s = 0.f, ss = 0.f;
#pragma unroll
    for (int j = 0; j < 3; ++j) {
        v[j] = xr[lane + 64 * j];
        s  += v[j].x + v[j].y + v[j].z + v[j].w;
        ss = fmaf(v[j].x, v[j].x, ss); ss = fmaf(v[j].y, v[j].y, ss);
        ss = fmaf(v[j].z, v[j].z, ss); ss = fmaf(v[j].w, v[j].w, ss);
    }
#pragma unroll
    for (int o = 32; o > 0; o >>= 1) { s += __shfl_xor(s, o); ss += __shfl_xor(ss, o); }
    float mu  = s * (1.f / DD);
    float var = fmaf(ss, 1.f / DD, -mu * mu);
    float rs  = rsqrtf(var + 1e-5f);
    const float4* g4 = (const float4*)gamma;
    const float4* b4 = (const float4*)beta;
    ushort4* outr = (ushort4*)(qn + (size_t)row * DD);
#pragma unroll
    for (int j = 0; j < 3; ++j) {
        int i4 = lane + 64 * j;
        float4 g = g4[i4], b = b4[i4];
        ushort4 o4;
        o4.x = f2bf((v[j].x - mu) * rs * g.x + b.x);
        o4.y = f2bf((v[j].y - mu) * rs * g.y + b.y);
        o4.z = f2bf((v[j].z - mu) * rs * g.z + b.z);
        o4.w = f2bf((v[j].w - mu) * rs * g.w + b.w);
        outr[i4] = o4;
    }
}

__global__ __launch_bounds__(256) void k_zero(float* __restrict__ out) {
    out[blockIdx.x * 256 + threadIdx.x] = 0.f;
}

// ---- K1: one block per (b, p). 16 value rows: fused LN + mm1 + band-sigmoid
//      + mm2, atomic epilogue. Small LDS (29.7 KB), high occupancy. ----
__global__ __launch_bounds__(256, 4) void k_attn(const float* __restrict__ x,
                                                 const float* __restrict__ gamma,
                                                 const float* __restrict__ beta,
                                                 const ushort* __restrict__ qn,
                                                 float* __restrict__ out) {
    __shared__ ushort Vl[16 * VS];      // 24832 B, row stride 776
    __shared__ float  Sl[4][TT][17];    // 4352 B, padded
    __shared__ ushort Wl[TT][TT];       // 512 B, row-major [t][r]

    int gid = blockIdx.x;
    int b = gid & 7, p = gid >> 3;      // p = 0..195
    int w = threadIdx.x >> 6, l = threadIdx.x & 63;
    int l15 = l & 15, lh = l >> 4;

    // ---- stage: wave w owns rows w*4..w*4+3; 16 lanes per row ----
    int r   = w * 4 + lh;
    int j16 = l15;
    const float* vrow = x + ((size_t)(1 + p) * NN + b * TT + r) * DD;
    float4 c[12];
#pragma unroll
    for (int k = 0; k < 12; ++k) c[k] = *(const float4*)(vrow + (j16 + 16 * k) * 4);

    // q A-frags for mm1 K-slice [w*192, w*192+192) (L2-hot, issued early)
    const ushort* qrow = qn + (size_t)(b * TT + l15) * DD + w * 192 + lh * 8;
    short8 qf[6];
#pragma unroll
    for (int s = 0; s < 6; ++s) qf[s] = *(const short8*)(qrow + s * 32);

    float s1 = 0.f, s2 = 0.f;
#pragma unroll
    for (int k = 0; k < 12; ++k) {
        float4 v = c[k];
        s1 += v.x + v.y + v.z + v.w;
        s2 = fmaf(v.x, v.x, s2); s2 = fmaf(v.y, v.y, s2);
        s2 = fmaf(v.z, v.z, s2); s2 = fmaf(v.w, v.w, s2);
    }
#pragma unroll
    for (int o = 1; o < 16; o <<= 1) { s1 += __shfl_xor(s1, o); s2 += __shfl_xor(s2, o); }
    float mu  = s1 * (1.f / DD);
    float var = fmaf(s2, 1.f / DD, -mu * mu);
    float rs  = rsqrtf(var + 1e-5f);

    const float4* g4 = (const float4*)gamma;
    const float4* b4 = (const float4*)beta;
#pragma unroll
    for (int k = 0; k < 12; ++k) {
        int c4 = j16 + 16 * k;
        float4 g = g4[c4], e = b4[c4];
        float4 v = c[k];
        ushort4 ut;
        ut.x = f2bf((v.x - mu) * rs * g.x + e.x);
        ut.y = f2bf((v.y - mu) * rs * g.y + e.y);
        ut.z = f2bf((v.z - mu) * rs * g.z + e.z);
        ut.w = f2bf((v.w - mu) * rs * g.w + e.w);
        *(ushort4*)&Vl[r * VS + c4 * 4] = ut;
    }
    __syncthreads();

    // ---- mm1: S[t][r] partial over this wave's K-slice (6 MFMA) ----
    f32x4 sacc = (f32x4){0.f, 0.f, 0.f, 0.f};
#pragma unroll
    for (int s = 0; s < 6; ++s) {
        int k0 = w * 192 + s * 32 + lh * 8;
        short8 bfr = *(const short8*)&Vl[l15 * VS + k0];
        sacc = __builtin_amdgcn_mfma_f32_16x16x32_bf16(qf[s], bfr, sacc, 0, 0, 0);
    }
#pragma unroll
    for (int q = 0; q < 4; ++q) Sl[w][lh * 4 + q][l15] = sacc[q];
    __syncthreads();

    // ---- reduce 4 K-slices + band-masked sigmoid -> Wl[t][r] ----
    {
        int t  = threadIdx.x >> 4, rr = threadIdx.x & 15;
        float s = Sl[0][t][rr] + Sl[1][t][rr] + Sl[2][t][rr] + Sl[3][t][rr];
        int dlt = rr - t;
        float wv = (dlt <= 2 && dlt >= -2)
                     ? (1.f / (1.f + __expf(-s * SCL)) - 0.5f) : 0.f;
        Wl[t][rr] = f2bf(wv);
    }
    __syncthreads();

    // ---- mm2: feat[16t x 768d] = W(16x32, hi-K zero) . V(32x768, hi rows zero)
    short8 wfrag = (short8){0, 0, 0, 0, 0, 0, 0, 0};
    if (lh < 2) wfrag = *(const short8*)&Wl[l15][lh * 8];
#pragma unroll
    for (int i = 0; i < 12; ++i) {
        int d0 = w * 192 + i * 16;
        union { ushort sv[8]; short8 v; } u;
        u.v = (short8){0, 0, 0, 0, 0, 0, 0, 0};
        if (lh < 2) {
#pragma unroll
            for (int j = 0; j < 8; ++j)
                u.sv[j] = Vl[(lh * 8 + j) * VS + d0 + l15];
        }
        f32x4 a = __builtin_amdgcn_mfma_f32_16x16x32_bf16(
            wfrag, u.v, (f32x4){0.f, 0.f, 0.f, 0.f}, 0, 0, 0);
#pragma unroll
        for (int q = 0; q < 4; ++q)
            atomicAdd(out + (size_t)(b * TT + lh * 4 + q) * DD + d0 + l15, a[q]);
    }
}

extern "C" void kernel_launch(void* const* d_in, const int* in_sizes, int n_in,
                              void* d_out, int out_size, void* d_ws, size_t ws_size,
                              hipStream_t stream) {
    const float* x     = (const float*)d_in[0];
    const float* gamma = (const float*)d_in[1];
    const float* beta  = (const float*)d_in[2];
    float* out = (float*)d_out;
    ushort* qn = (ushort*)d_ws;   // 128*768 bf16 = 196,608 B

    k_zero<<<NN * DD / 256, 256, 0, stream>>>(out);
    k_lnq<<<NN / 4, 256, 0, stream>>>(x, gamma, beta, qn);
    k_attn<<<8 * PP, 256, 0, stream>>>(x, gamma, beta, qn, out);
}

// Round 9
// 53.141 us; speedup vs baseline: 1.6509x; 1.6509x over previous
//
#include <hip/hip_runtime.h>

#define NN 128
#define DD 768
#define TT 16
#define PP 196
#define SCL 0.03608439182435161f  // 1/sqrt(768)
#define VS 776                    // Vl row stride (ushorts): 16B-aligned, bank-skewed

typedef short short8 __attribute__((ext_vector_type(8)));
typedef short short4v __attribute__((ext_vector_type(4)));
typedef float f32x4 __attribute__((ext_vector_type(4)));

static __device__ __forceinline__ ushort f2bf(float f) {
    union { float f; unsigned int u; } a; a.f = f;
    unsigned int r = a.u + 0x7fffu + ((a.u >> 16) & 1u);
    return (ushort)(r >> 16);
}
static __device__ __forceinline__ float bf2f(ushort u) {
    union { unsigned int u; float f; } c; c.u = (unsigned int)u << 16; return c.f;
}

// ---------------- K0: LayerNorm of the 128 cls rows -> qn bf16 ----------------
__global__ __launch_bounds__(256) void k_lnq(const float* __restrict__ x,
                                             const float* __restrict__ gamma,
                                             const float* __restrict__ beta,
                                             ushort* __restrict__ qn) {
    int row  = (blockIdx.x << 2) + (threadIdx.x >> 6);   // 0..127
    int lane = threadIdx.x & 63;
    const float4* xr = (const float4*)(x + (size_t)row * DD);
    float4 v[3];
    float s = 0.f, ss = 0.f;
#pragma unroll
    for (int j = 0; j < 3; ++j) {
        v[j] = xr[lane + 64 * j];
        s  += v[j].x + v[j].y + v[j].z + v[j].w;
        ss = fmaf(v[j].x, v[j].x, ss); ss = fmaf(v[j].y, v[j].y, ss);
        ss = fmaf(v[j].z, v[j].z, ss); ss = fmaf(v[j].w, v[j].w, ss);
    }
#pragma unroll
    for (int o = 32; o > 0; o >>= 1) { s += __shfl_xor(s, o); ss += __shfl_xor(ss, o); }
    float mu  = s * (1.f / DD);
    float var = fmaf(ss, 1.f / DD, -mu * mu);
    float rs  = rsqrtf(var + 1e-5f);
    const float4* g4 = (const float4*)gamma;
    const float4* b4 = (const float4*)beta;
    ushort4* outr = (ushort4*)(qn + (size_t)row * DD);
#pragma unroll
    for (int j = 0; j < 3; ++j) {
        int i4 = lane + 64 * j;
        float4 g = g4[i4], b = b4[i4];
        ushort4 o4;
        o4.x = f2bf((v[j].x - mu) * rs * g.x + b.x);
        o4.y = f2bf((v[j].y - mu) * rs * g.y + b.y);
        o4.z = f2bf((v[j].z - mu) * rs * g.z + b.z);
        o4.w = f2bf((v[j].w - mu) * rs * g.w + b.w);
        outr[i4] = o4;
    }
}

__global__ __launch_bounds__(256) void k_zero(float* __restrict__ out) {
    out[blockIdx.x * 256 + threadIdx.x] = 0.f;
}

// ---- K1: one block per (b, p). 16 value rows: fused LN + mm1 + band-sigmoid
//      + mm2. Epilogue: private bf16 partial slot (no atomics). ----
template<bool USE_PART>
__global__ __launch_bounds__(256, 4) void k_attn(const float* __restrict__ x,
                                                 const float* __restrict__ gamma,
                                                 const float* __restrict__ beta,
                                                 const ushort* __restrict__ qn,
                                                 ushort* __restrict__ part,
                                                 float* __restrict__ out) {
    __shared__ ushort Vl[16 * VS];      // 24832 B, row stride 776
    __shared__ float  Sl[4][TT][17];    // 4352 B, padded
    __shared__ ushort Wl[TT][TT];       // 512 B, row-major [t][r]

    int gid = blockIdx.x;
    int b = gid & 7, p = gid >> 3;      // p = 0..195
    int w = threadIdx.x >> 6, l = threadIdx.x & 63;
    int l15 = l & 15, lh = l >> 4;

    // ---- stage: wave w owns rows w*4..w*4+3; 16 lanes per row ----
    int r   = w * 4 + lh;
    int j16 = l15;
    const float* vrow = x + ((size_t)(1 + p) * NN + b * TT + r) * DD;
    float4 c[12];
#pragma unroll
    for (int k = 0; k < 12; ++k) c[k] = *(const float4*)(vrow + (j16 + 16 * k) * 4);

    // q A-frags for mm1 K-slice [w*192, w*192+192) (L2-hot, issued early)
    const ushort* qrow = qn + (size_t)(b * TT + l15) * DD + w * 192 + lh * 8;
    short8 qf[6];
#pragma unroll
    for (int s = 0; s < 6; ++s) qf[s] = *(const short8*)(qrow + s * 32);

    float s1 = 0.f, s2 = 0.f;
#pragma unroll
    for (int k = 0; k < 12; ++k) {
        float4 v = c[k];
        s1 += v.x + v.y + v.z + v.w;
        s2 = fmaf(v.x, v.x, s2); s2 = fmaf(v.y, v.y, s2);
        s2 = fmaf(v.z, v.z, s2); s2 = fmaf(v.w, v.w, s2);
    }
#pragma unroll
    for (int o = 1; o < 16; o <<= 1) { s1 += __shfl_xor(s1, o); s2 += __shfl_xor(s2, o); }
    float mu  = s1 * (1.f / DD);
    float var = fmaf(s2, 1.f / DD, -mu * mu);
    float rs  = rsqrtf(var + 1e-5f);

    const float4* g4 = (const float4*)gamma;
    const float4* b4 = (const float4*)beta;
#pragma unroll
    for (int k = 0; k < 12; ++k) {
        int c4 = j16 + 16 * k;
        float4 g = g4[c4], e = b4[c4];
        float4 v = c[k];
        ushort4 ut;
        ut.x = f2bf((v.x - mu) * rs * g.x + e.x);
        ut.y = f2bf((v.y - mu) * rs * g.y + e.y);
        ut.z = f2bf((v.z - mu) * rs * g.z + e.z);
        ut.w = f2bf((v.w - mu) * rs * g.w + e.w);
        *(ushort4*)&Vl[r * VS + c4 * 4] = ut;
    }
    __syncthreads();

    // ---- mm1: S[t][r] partial over this wave's K-slice (6 MFMA) ----
    f32x4 sacc = (f32x4){0.f, 0.f, 0.f, 0.f};
#pragma unroll
    for (int s = 0; s < 6; ++s) {
        int k0 = w * 192 + s * 32 + lh * 8;
        short8 bfr = *(const short8*)&Vl[l15 * VS + k0];
        sacc = __builtin_amdgcn_mfma_f32_16x16x32_bf16(qf[s], bfr, sacc, 0, 0, 0);
    }
#pragma unroll
    for (int q = 0; q < 4; ++q) Sl[w][lh * 4 + q][l15] = sacc[q];
    __syncthreads();

    // ---- reduce 4 K-slices + band-masked sigmoid -> Wl[t][r] ----
    {
        int t  = threadIdx.x >> 4, rr = threadIdx.x & 15;
        float s = Sl[0][t][rr] + Sl[1][t][rr] + Sl[2][t][rr] + Sl[3][t][rr];
        int dlt = rr - t;
        float wv = (dlt <= 2 && dlt >= -2)
                     ? (1.f / (1.f + __expf(-s * SCL)) - 0.5f) : 0.f;
        Wl[t][rr] = f2bf(wv);
    }
    __syncthreads();

    // ---- mm2: feat[16t x 768d] = W(16x32, hi-K zero) . V(32x768, hi rows zero)
    short8 wfrag = (short8){0, 0, 0, 0, 0, 0, 0, 0};
    if (lh < 2) wfrag = *(const short8*)&Wl[l15][lh * 8];
    ushort* myp = part + ((size_t)(p * 8 + b)) * (TT * DD);
#pragma unroll
    for (int i = 0; i < 12; ++i) {
        int d0 = w * 192 + i * 16;
        union { ushort sv[8]; short8 v; } u;
        u.v = (short8){0, 0, 0, 0, 0, 0, 0, 0};
        if (lh < 2) {
#pragma unroll
            for (int j = 0; j < 8; ++j)
                u.sv[j] = Vl[(lh * 8 + j) * VS + d0 + l15];
        }
        f32x4 a = __builtin_amdgcn_mfma_f32_16x16x32_bf16(
            wfrag, u.v, (f32x4){0.f, 0.f, 0.f, 0.f}, 0, 0, 0);
#pragma unroll
        for (int q = 0; q < 4; ++q) {
            int t = lh * 4 + q;
            if (USE_PART) {
                myp[t * DD + d0 + l15] = f2bf(a[q]);
            } else {
                atomicAdd(out + (size_t)(b * TT + t) * DD + d0 + l15, a[q]);
            }
        }
    }
}

// ---------------- K2: reduce 196 bf16 p-partials ----------------
__global__ __launch_bounds__(256) void k_reduce(const ushort* __restrict__ part,
                                                float* __restrict__ out) {
    int e = (blockIdx.x * 256 + threadIdx.x) * 4;   // elem index over 98304
    int b = e / (TT * DD);
    int rem = e - b * (TT * DD);
    const ushort* src = part + (size_t)b * (TT * DD) + rem;
    float s0 = 0.f, s1 = 0.f, s2 = 0.f, s3 = 0.f;
#pragma unroll 4
    for (int p = 0; p < PP; ++p) {
        union { short4v v; ushort sv[4]; } u;
        u.v = *(const short4v*)(src + (size_t)p * 8 * (TT * DD));
        s0 += bf2f(u.sv[0]); s1 += bf2f(u.sv[1]);
        s2 += bf2f(u.sv[2]); s3 += bf2f(u.sv[3]);
    }
    *(float4*)(out + e) = (float4){s0, s1, s2, s3};
}

extern "C" void kernel_launch(void* const* d_in, const int* in_sizes, int n_in,
                              void* d_out, int out_size, void* d_ws, size_t ws_size,
                              hipStream_t stream) {
    const float* x     = (const float*)d_in[0];
    const float* gamma = (const float*)d_in[1];
    const float* beta  = (const float*)d_in[2];
    float* out = (float*)d_out;

    const size_t qn_bytes   = (size_t)NN * DD * 2;                  // 196,608
    const size_t part_bytes = (size_t)PP * 8 * TT * DD * 2;         // 38,535,168
    ushort* qn   = (ushort*)d_ws;
    ushort* part = (ushort*)((char*)d_ws + qn_bytes);
    bool use_part = ws_size >= qn_bytes + part_bytes;

    k_lnq<<<NN / 4, 256, 0, stream>>>(x, gamma, beta, qn);
    if (use_part) {
        k_attn<true><<<8 * PP, 256, 0, stream>>>(x, gamma, beta, qn, part, out);
        k_reduce<<<96, 256, 0, stream>>>(part, out);
    } else {
        k_zero<<<NN * DD / 256, 256, 0, stream>>>(out);
        k_attn<false><<<8 * PP, 256, 0, stream>>>(x, gamma, beta, qn, part, out);
    }
}

// Round 10
// 43.354 us; speedup vs baseline: 2.0236x; 1.2257x over previous
//
#include <hip/hip_runtime.h>

#define NN 128
#define DD 768
#define TT 16
#define PP 196
#define SCL 0.03608439182435161f  // 1/sqrt(768)
#define VS 776                    // Vl row stride (ushorts): 16B-aligned, bank-skewed

typedef short short8 __attribute__((ext_vector_type(8)));
typedef short short4v __attribute__((ext_vector_type(4)));
typedef float f32x4 __attribute__((ext_vector_type(4)));

static __device__ __forceinline__ ushort f2bf(float f) {
    union { float f; unsigned int u; } a; a.f = f;
    unsigned int r = a.u + 0x7fffu + ((a.u >> 16) & 1u);
    return (ushort)(r >> 16);
}
static __device__ __forceinline__ float bf2f(ushort u) {
    union { unsigned int u; float f; } c; c.u = (unsigned int)u << 16; return c.f;
}

// ---------------- K0: LayerNorm of the 128 cls rows -> qn bf16 ----------------
__global__ __launch_bounds__(256) void k_lnq(const float* __restrict__ x,
                                             const float* __restrict__ gamma,
                                             const float* __restrict__ beta,
                                             ushort* __restrict__ qn) {
    int row  = (blockIdx.x << 2) + (threadIdx.x >> 6);   // 0..127
    int lane = threadIdx.x & 63;
    const float4* xr = (const float4*)(x + (size_t)row * DD);
    float4 v[3];
    float s = 0.f, ss = 0.f;
#pragma unroll
    for (int j = 0; j < 3; ++j) {
        v[j] = xr[lane + 64 * j];
        s  += v[j].x + v[j].y + v[j].z + v[j].w;
        ss = fmaf(v[j].x, v[j].x, ss); ss = fmaf(v[j].y, v[j].y, ss);
        ss = fmaf(v[j].z, v[j].z, ss); ss = fmaf(v[j].w, v[j].w, ss);
    }
#pragma unroll
    for (int o = 32; o > 0; o >>= 1) { s += __shfl_xor(s, o); ss += __shfl_xor(ss, o); }
    float mu  = s * (1.f / DD);
    float var = fmaf(ss, 1.f / DD, -mu * mu);
    float rs  = rsqrtf(var + 1e-5f);
    const float4* g4 = (const float4*)gamma;
    const float4* b4 = (const float4*)beta;
    ushort4* outr = (ushort4*)(qn + (size_t)row * DD);
#pragma unroll
    for (int j = 0; j < 3; ++j) {
        int i4 = lane + 64 * j;
        float4 g = g4[i4], b = b4[i4];
        ushort4 o4;
        o4.x = f2bf((v[j].x - mu) * rs * g.x + b.x);
        o4.y = f2bf((v[j].y - mu) * rs * g.y + b.y);
        o4.z = f2bf((v[j].z - mu) * rs * g.z + b.z);
        o4.w = f2bf((v[j].w - mu) * rs * g.w + b.w);
        outr[i4] = o4;
    }
}

__global__ __launch_bounds__(256) void k_zero(float* __restrict__ out) {
    out[blockIdx.x * 256 + threadIdx.x] = 0.f;
}

// ---- K1: one block per (b, p). 16 value rows: fused LN + mm1 + band-sigmoid
//      + mm2. Epilogue: fragment-order bf16 partial slot, fully coalesced. ----
template<bool USE_PART>
__global__ __launch_bounds__(256, 4) void k_attn(const float* __restrict__ x,
                                                 const float* __restrict__ gamma,
                                                 const float* __restrict__ beta,
                                                 const ushort* __restrict__ qn,
                                                 ushort* __restrict__ part,
                                                 float* __restrict__ out) {
    __shared__ ushort Vl[16 * VS];      // 24832 B, row stride 776
    __shared__ float  Sl[4][TT][17];    // 4352 B, padded
    __shared__ ushort Wl[TT][TT];       // 512 B, row-major [t][r]

    int gid = blockIdx.x;
    int b = gid & 7, p = gid >> 3;      // p = 0..195
    int w = threadIdx.x >> 6, l = threadIdx.x & 63;
    int l15 = l & 15, lh = l >> 4;

    // ---- stage: wave w owns rows w*4..w*4+3; 16 lanes per row ----
    int r   = w * 4 + lh;
    int j16 = l15;
    const float* vrow = x + ((size_t)(1 + p) * NN + b * TT + r) * DD;
    float4 c[12];
#pragma unroll
    for (int k = 0; k < 12; ++k) c[k] = *(const float4*)(vrow + (j16 + 16 * k) * 4);

    // q A-frags for mm1 K-slice [w*192, w*192+192) (L2-hot, issued early)
    const ushort* qrow = qn + (size_t)(b * TT + l15) * DD + w * 192 + lh * 8;
    short8 qf[6];
#pragma unroll
    for (int s = 0; s < 6; ++s) qf[s] = *(const short8*)(qrow + s * 32);

    float s1 = 0.f, s2 = 0.f;
#pragma unroll
    for (int k = 0; k < 12; ++k) {
        float4 v = c[k];
        s1 += v.x + v.y + v.z + v.w;
        s2 = fmaf(v.x, v.x, s2); s2 = fmaf(v.y, v.y, s2);
        s2 = fmaf(v.z, v.z, s2); s2 = fmaf(v.w, v.w, s2);
    }
#pragma unroll
    for (int o = 1; o < 16; o <<= 1) { s1 += __shfl_xor(s1, o); s2 += __shfl_xor(s2, o); }
    float mu  = s1 * (1.f / DD);
    float var = fmaf(s2, 1.f / DD, -mu * mu);
    float rs  = rsqrtf(var + 1e-5f);

    const float4* g4 = (const float4*)gamma;
    const float4* b4 = (const float4*)beta;
#pragma unroll
    for (int k = 0; k < 12; ++k) {
        int c4 = j16 + 16 * k;
        float4 g = g4[c4], e = b4[c4];
        float4 v = c[k];
        ushort4 ut;
        ut.x = f2bf((v.x - mu) * rs * g.x + e.x);
        ut.y = f2bf((v.y - mu) * rs * g.y + e.y);
        ut.z = f2bf((v.z - mu) * rs * g.z + e.z);
        ut.w = f2bf((v.w - mu) * rs * g.w + e.w);
        *(ushort4*)&Vl[r * VS + c4 * 4] = ut;
    }
    __syncthreads();

    // ---- mm1: S[t][r] partial over this wave's K-slice (6 MFMA) ----
    f32x4 sacc = (f32x4){0.f, 0.f, 0.f, 0.f};
#pragma unroll
    for (int s = 0; s < 6; ++s) {
        int k0 = w * 192 + s * 32 + lh * 8;
        short8 bfr = *(const short8*)&Vl[l15 * VS + k0];
        sacc = __builtin_amdgcn_mfma_f32_16x16x32_bf16(qf[s], bfr, sacc, 0, 0, 0);
    }
#pragma unroll
    for (int q = 0; q < 4; ++q) Sl[w][lh * 4 + q][l15] = sacc[q];
    __syncthreads();

    // ---- reduce 4 K-slices + band-masked sigmoid -> Wl[t][r] ----
    {
        int t  = threadIdx.x >> 4, rr = threadIdx.x & 15;
        float s = Sl[0][t][rr] + Sl[1][t][rr] + Sl[2][t][rr] + Sl[3][t][rr];
        int dlt = rr - t;
        float wv = (dlt <= 2 && dlt >= -2)
                     ? (1.f / (1.f + __expf(-s * SCL)) - 0.5f) : 0.f;
        Wl[t][rr] = f2bf(wv);
    }
    __syncthreads();

    // ---- mm2: feat[16t x 768d] = W(16x32, hi-K zero) . V(32x768, hi rows zero)
    short8 wfrag = (short8){0, 0, 0, 0, 0, 0, 0, 0};
    if (lh < 2) wfrag = *(const short8*)&Wl[l15][lh * 8];
    ushort* myp = part + ((size_t)(p * 8 + b)) * (TT * DD);
#pragma unroll
    for (int i = 0; i < 12; ++i) {
        int d0 = w * 192 + i * 16;
        union { ushort sv[8]; short8 v; } u;
        u.v = (short8){0, 0, 0, 0, 0, 0, 0, 0};
        if (lh < 2) {
#pragma unroll
            for (int j = 0; j < 8; ++j)
                u.sv[j] = Vl[(lh * 8 + j) * VS + d0 + l15];
        }
        f32x4 a = __builtin_amdgcn_mfma_f32_16x16x32_bf16(
            wfrag, u.v, (f32x4){0.f, 0.f, 0.f, 0.f}, 0, 0, 0);
        if (USE_PART) {
            // fragment-order store: fully coalesced 8B/lane
            ushort4 pk;
            pk.x = f2bf(a[0]); pk.y = f2bf(a[1]);
            pk.z = f2bf(a[2]); pk.w = f2bf(a[3]);
            *(ushort4*)&myp[((w * 12 + i) * 64 + l) * 4] = pk;
        } else {
#pragma unroll
            for (int q = 0; q < 4; ++q)
                atomicAdd(out + (size_t)(b * TT + lh * 4 + q) * DD + d0 + l15, a[q]);
        }
    }
}

// ---- K2: reduce 196 fragment-order bf16 partials; 7 p-chunks x 96 e-blocks --
__global__ __launch_bounds__(256) void k_reduce(const ushort* __restrict__ part,
                                                float* __restrict__ out) {
    int bid = blockIdx.x;
    int pc  = bid % 7;                       // p-chunk: 28 slices
    int g   = (bid / 7) * 256 + threadIdx.x; // 0..24575: (b, pos4)
    int b    = g / 3072;
    int pos4 = g - b * 3072;                 // float4-group within slice
    const ushort* src = part + (size_t)b * (TT * DD) + pos4 * 4;

    float s0 = 0.f, s1 = 0.f, s2 = 0.f, s3 = 0.f;
#pragma unroll 4
    for (int p = pc * 28; p < pc * 28 + 28; ++p) {
        union { short4v v; ushort sv[4]; } u;
        u.v = *(const short4v*)(src + (size_t)p * 8 * (TT * DD));
        s0 += bf2f(u.sv[0]); s1 += bf2f(u.sv[1]);
        s2 += bf2f(u.sv[2]); s3 += bf2f(u.sv[3]);
    }
    // decode fragment position -> (t, d)
    int fp    = pos4 * 4;
    int chunk = fp >> 8;           // w*12 + i
    int l     = (fp >> 2) & 63;
    int w     = chunk / 12, i = chunk - w * 12;
    int lh    = l >> 4,   l15 = l & 15;
    int d     = w * 192 + i * 16 + l15;
    float* dst = out + ((size_t)b * TT + lh * 4) * DD + d;
    atomicAdd(dst,            s0);
    atomicAdd(dst + 1 * DD,   s1);
    atomicAdd(dst + 2 * DD,   s2);
    atomicAdd(dst + 3 * DD,   s3);
}

extern "C" void kernel_launch(void* const* d_in, const int* in_sizes, int n_in,
                              void* d_out, int out_size, void* d_ws, size_t ws_size,
                              hipStream_t stream) {
    const float* x     = (const float*)d_in[0];
    const float* gamma = (const float*)d_in[1];
    const float* beta  = (const float*)d_in[2];
    float* out = (float*)d_out;

    const size_t qn_bytes   = (size_t)NN * DD * 2;                  // 196,608
    const size_t part_bytes = (size_t)PP * 8 * TT * DD * 2;         // 38,535,168
    ushort* qn   = (ushort*)d_ws;
    ushort* part = (ushort*)((char*)d_ws + qn_bytes);
    bool use_part = ws_size >= qn_bytes + part_bytes;

    k_zero<<<NN * DD / 256, 256, 0, stream>>>(out);
    k_lnq<<<NN / 4, 256, 0, stream>>>(x, gamma, beta, qn);
    if (use_part) {
        k_attn<true><<<8 * PP, 256, 0, stream>>>(x, gamma, beta, qn, part, out);
        k_reduce<<<7 * 96, 256, 0, stream>>>(part, out);
    } else {
        k_attn<false><<<8 * PP, 256, 0, stream>>>(x, gamma, beta, qn, part, out);
    }
}

// Round 11
// 41.387 us; speedup vs baseline: 2.1197x; 1.0475x over previous
//
#include <hip/hip_runtime.h>

#define NN 128
#define DD 768
#define TT 16
#define PP 196
#define NSL 98                    // slices per b, 2 p each
#define SCL 0.03608439182435161f  // 1/sqrt(768)
#define VS 776                    // Vl row stride (ushorts): 16B-aligned, bank-skewed

typedef short short8 __attribute__((ext_vector_type(8)));
typedef short short4v __attribute__((ext_vector_type(4)));
typedef float f32x4 __attribute__((ext_vector_type(4)));

static __device__ __forceinline__ ushort f2bf(float f) {
    union { float f; unsigned int u; } a; a.f = f;
    unsigned int r = a.u + 0x7fffu + ((a.u >> 16) & 1u);
    return (ushort)(r >> 16);
}
static __device__ __forceinline__ float bf2f(ushort u) {
    union { unsigned int u; float f; } c; c.u = (unsigned int)u << 16; return c.f;
}

// -------- K0: zero out (3 float4/thread) + LayerNorm of 128 cls rows --------
__global__ __launch_bounds__(256) void k_lnq(const float* __restrict__ x,
                                             const float* __restrict__ gamma,
                                             const float* __restrict__ beta,
                                             ushort* __restrict__ qn,
                                             float* __restrict__ out) {
    int zi = blockIdx.x * 256 + threadIdx.x;   // 0..8191
    float4 z = {0.f, 0.f, 0.f, 0.f};
    ((float4*)out)[zi]         = z;
    ((float4*)out)[zi + 8192]  = z;
    ((float4*)out)[zi + 16384] = z;

    int row  = (blockIdx.x << 2) + (threadIdx.x >> 6);   // 0..127
    int lane = threadIdx.x & 63;
    const float4* xr = (const float4*)(x + (size_t)row * DD);
    float4 v[3];
    float s = 0.f, ss = 0.f;
#pragma unroll
    for (int j = 0; j < 3; ++j) {
        v[j] = xr[lane + 64 * j];
        s  += v[j].x + v[j].y + v[j].z + v[j].w;
        ss = fmaf(v[j].x, v[j].x, ss); ss = fmaf(v[j].y, v[j].y, ss);
        ss = fmaf(v[j].z, v[j].z, ss); ss = fmaf(v[j].w, v[j].w, ss);
    }
#pragma unroll
    for (int o = 32; o > 0; o >>= 1) { s += __shfl_xor(s, o); ss += __shfl_xor(ss, o); }
    float mu  = s * (1.f / DD);
    float var = fmaf(ss, 1.f / DD, -mu * mu);
    float rs  = rsqrtf(var + 1e-5f);
    const float4* g4 = (const float4*)gamma;
    const float4* b4 = (const float4*)beta;
    ushort4* outr = (ushort4*)(qn + (size_t)row * DD);
#pragma unroll
    for (int j = 0; j < 3; ++j) {
        int i4 = lane + 64 * j;
        float4 g = g4[i4], b = b4[i4];
        ushort4 o4;
        o4.x = f2bf((v[j].x - mu) * rs * g.x + b.x);
        o4.y = f2bf((v[j].y - mu) * rs * g.y + b.y);
        o4.z = f2bf((v[j].z - mu) * rs * g.z + b.z);
        o4.w = f2bf((v[j].w - mu) * rs * g.w + b.w);
        outr[i4] = o4;
    }
}

// ---- K1: one block per (b, sl). 2 p per block, fused LN + mm1 + band-sigmoid
//      + mm2 with register accumulation across the 2 p. Prefetch p1 during p0.
template<bool USE_PART>
__global__ __launch_bounds__(256, 3) void k_attn(const float* __restrict__ x,
                                                 const float* __restrict__ gamma,
                                                 const float* __restrict__ beta,
                                                 const ushort* __restrict__ qn,
                                                 ushort* __restrict__ part,
                                                 float* __restrict__ out) {
    __shared__ ushort Vl[16 * VS];      // 24832 B, row stride 776
    __shared__ float  Sl[4][TT][17];    // 4352 B, padded
    __shared__ ushort Wl[TT][TT];       // 512 B, row-major [t][r]

    int gid = blockIdx.x;
    int b = gid & 7, sl = gid >> 3;     // sl = 0..97
    int w = threadIdx.x >> 6, l = threadIdx.x & 63;
    int l15 = l & 15, lh = l >> 4;
    int r = w * 4 + lh, j16 = l15;

    // q A-frags for mm1 K-slice [w*192, w*192+192)
    const ushort* qrow = qn + (size_t)(b * TT + l15) * DD + w * 192 + lh * 8;
    short8 qf[6];
#pragma unroll
    for (int s = 0; s < 6; ++s) qf[s] = *(const short8*)(qrow + s * 32);

    f32x4 acc[12];
#pragma unroll
    for (int i = 0; i < 12; ++i) acc[i] = (f32x4){0.f, 0.f, 0.f, 0.f};

    const float4* g4 = (const float4*)gamma;
    const float4* b4 = (const float4*)beta;
    float4 c[12];

#define GLOADP(P)                                                                 \
    {                                                                             \
        const float* vrow = x + ((size_t)(1 + (P)) * NN + b * TT + r) * DD;       \
        _Pragma("unroll")                                                         \
        for (int k = 0; k < 12; ++k) c[k] = *(const float4*)(vrow + (j16 + 16 * k) * 4); \
    }

#define LNPACK()                                                                  \
    {                                                                             \
        float s1 = 0.f, s2 = 0.f;                                                 \
        _Pragma("unroll")                                                         \
        for (int k = 0; k < 12; ++k) {                                            \
            float4 v = c[k];                                                      \
            s1 += v.x + v.y + v.z + v.w;                                          \
            s2 = fmaf(v.x, v.x, s2); s2 = fmaf(v.y, v.y, s2);                     \
            s2 = fmaf(v.z, v.z, s2); s2 = fmaf(v.w, v.w, s2);                     \
        }                                                                         \
        _Pragma("unroll")                                                         \
        for (int o = 1; o < 16; o <<= 1) {                                        \
            s1 += __shfl_xor(s1, o); s2 += __shfl_xor(s2, o);                     \
        }                                                                         \
        float mu  = s1 * (1.f / DD);                                              \
        float var = fmaf(s2, 1.f / DD, -mu * mu);                                 \
        float rs  = rsqrtf(var + 1e-5f);                                          \
        _Pragma("unroll")                                                         \
        for (int k = 0; k < 12; ++k) {                                            \
            int c4 = j16 + 16 * k;                                                \
            float4 g = g4[c4], e = b4[c4];                                        \
            float4 v = c[k];                                                      \
            ushort4 ut;                                                           \
            ut.x = f2bf((v.x - mu) * rs * g.x + e.x);                             \
            ut.y = f2bf((v.y - mu) * rs * g.y + e.y);                             \
            ut.z = f2bf((v.z - mu) * rs * g.z + e.z);                             \
            ut.w = f2bf((v.w - mu) * rs * g.w + e.w);                             \
            *(ushort4*)&Vl[r * VS + c4 * 4] = ut;                                 \
        }                                                                         \
    }

#define MM1W()                                                                    \
    {                                                                             \
        f32x4 sacc = (f32x4){0.f, 0.f, 0.f, 0.f};                                 \
        _Pragma("unroll")                                                         \
        for (int s = 0; s < 6; ++s) {                                             \
            int k0 = w * 192 + s * 32 + lh * 8;                                   \
            short8 bfr = *(const short8*)&Vl[l15 * VS + k0];                      \
            sacc = __builtin_amdgcn_mfma_f32_16x16x32_bf16(qf[s], bfr, sacc, 0, 0, 0); \
        }                                                                         \
        _Pragma("unroll")                                                         \
        for (int q = 0; q < 4; ++q) Sl[w][lh * 4 + q][l15] = sacc[q];             \
        __syncthreads();                                                          \
        {                                                                         \
            int t  = threadIdx.x >> 4, rr = threadIdx.x & 15;                     \
            float s = Sl[0][t][rr] + Sl[1][t][rr] + Sl[2][t][rr] + Sl[3][t][rr];  \
            int dlt = rr - t;                                                     \
            float wv = (dlt <= 2 && dlt >= -2)                                    \
                         ? (1.f / (1.f + __expf(-s * SCL)) - 0.5f) : 0.f;         \
            Wl[t][rr] = f2bf(wv);                                                 \
        }                                                                         \
        __syncthreads();                                                          \
    }

#define MM2()                                                                     \
    {                                                                             \
        short8 wfrag = (short8){0, 0, 0, 0, 0, 0, 0, 0};                          \
        if (lh < 2) wfrag = *(const short8*)&Wl[l15][lh * 8];                     \
        _Pragma("unroll")                                                         \
        for (int i = 0; i < 12; ++i) {                                            \
            int d0 = w * 192 + i * 16;                                            \
            union { ushort sv[8]; short8 v; } u;                                  \
            u.v = (short8){0, 0, 0, 0, 0, 0, 0, 0};                               \
            if (lh < 2) {                                                         \
                _Pragma("unroll")                                                 \
                for (int j = 0; j < 8; ++j)                                       \
                    u.sv[j] = Vl[(lh * 8 + j) * VS + d0 + l15];                   \
            }                                                                     \
            acc[i] = __builtin_amdgcn_mfma_f32_16x16x32_bf16(wfrag, u.v, acc[i], 0, 0, 0); \
        }                                                                         \
    }

    GLOADP(sl * 2);
    LNPACK();
    __syncthreads();
    GLOADP(sl * 2 + 1);   // prefetch p1 during p0 compute
    MM1W();
    MM2();
    __syncthreads();      // Vl free
    LNPACK();
    __syncthreads();
    MM1W();
    MM2();

#undef GLOADP
#undef LNPACK
#undef MM1W
#undef MM2

    // ---- epilogue ----
    if (USE_PART) {
        ushort* myp = part + (size_t)(sl * 8 + b) * (TT * DD);
#pragma unroll
        for (int i = 0; i < 12; ++i) {
            ushort4 pk;
            pk.x = f2bf(acc[i][0]); pk.y = f2bf(acc[i][1]);
            pk.z = f2bf(acc[i][2]); pk.w = f2bf(acc[i][3]);
            *(ushort4*)&myp[((w * 12 + i) * 64 + l) * 4] = pk;
        }
    } else {
#pragma unroll
        for (int i = 0; i < 12; ++i) {
            int d0 = w * 192 + i * 16;
#pragma unroll
            for (int q = 0; q < 4; ++q)
                atomicAdd(out + (size_t)(b * TT + lh * 4 + q) * DD + d0 + l15, acc[i][q]);
        }
    }
}

// ---- K2: reduce 98 fragment-order bf16 partials; 7 p-chunks x 96 e-blocks ---
__global__ __launch_bounds__(256) void k_reduce(const ushort* __restrict__ part,
                                                float* __restrict__ out) {
    int bid = blockIdx.x;
    int pc  = bid % 7;                       // slice-chunk: 14 slices
    int g   = (bid / 7) * 256 + threadIdx.x; // 0..24575: (b, pos4)
    int b    = g / 3072;
    int pos4 = g - b * 3072;                 // float4-group within slice
    const ushort* src = part + (size_t)b * (TT * DD) + pos4 * 4;

    float s0 = 0.f, s1 = 0.f, s2 = 0.f, s3 = 0.f;
#pragma unroll 2
    for (int s = pc * 14; s < pc * 14 + 14; ++s) {
        union { short4v v; ushort sv[4]; } u;
        u.v = *(const short4v*)(src + (size_t)s * 8 * (TT * DD));
        s0 += bf2f(u.sv[0]); s1 += bf2f(u.sv[1]);
        s2 += bf2f(u.sv[2]); s3 += bf2f(u.sv[3]);
    }
    // decode fragment position -> (t, d)
    int fp    = pos4 * 4;
    int chunk = fp >> 8;           // w*12 + i
    int l     = (fp >> 2) & 63;
    int w     = chunk / 12, i = chunk - w * 12;
    int lh    = l >> 4,   l15 = l & 15;
    int d     = w * 192 + i * 16 + l15;
    float* dst = out + ((size_t)b * TT + lh * 4) * DD + d;
    atomicAdd(dst,          s0);
    atomicAdd(dst + 1 * DD, s1);
    atomicAdd(dst + 2 * DD, s2);
    atomicAdd(dst + 3 * DD, s3);
}

extern "C" void kernel_launch(void* const* d_in, const int* in_sizes, int n_in,
                              void* d_out, int out_size, void* d_ws, size_t ws_size,
                              hipStream_t stream) {
    const float* x     = (const float*)d_in[0];
    const float* gamma = (const float*)d_in[1];
    const float* beta  = (const float*)d_in[2];
    float* out = (float*)d_out;

    const size_t qn_bytes   = (size_t)NN * DD * 2;                  // 196,608
    const size_t part_bytes = (size_t)NSL * 8 * TT * DD * 2;        // 19,267,584
    ushort* qn   = (ushort*)d_ws;
    ushort* part = (ushort*)((char*)d_ws + qn_bytes);
    bool use_part = ws_size >= qn_bytes + part_bytes;

    k_lnq<<<NN / 4, 256, 0, stream>>>(x, gamma, beta, qn, out);
    if (use_part) {
        k_attn<true><<<8 * NSL, 256, 0, stream>>>(x, gamma, beta, qn, part, out);
        k_reduce<<<7 * 96, 256, 0, stream>>>(part, out);
    } else {
        k_attn<false><<<8 * NSL, 256, 0, stream>>>(x, gamma, beta, qn, part, out);
    }
}

// Round 12
// 40.765 us; speedup vs baseline: 2.1521x; 1.0153x over previous
//
#include <hip/hip_runtime.h>

#define NN 128
#define DD 768
#define TT 16
#define PP 196
#define NSL 98                    // slices per b, 2 p each
#define SCL 0.03608439182435161f  // 1/sqrt(768)
#define VS 776                    // Vl row stride (ushorts): 16B-aligned, bank-skewed

typedef short short8 __attribute__((ext_vector_type(8)));
typedef short short4v __attribute__((ext_vector_type(4)));
typedef float f32x4 __attribute__((ext_vector_type(4)));

static __device__ __forceinline__ ushort f2bf(float f) {
    union { float f; unsigned int u; } a; a.f = f;
    unsigned int r = a.u + 0x7fffu + ((a.u >> 16) & 1u);
    return (ushort)(r >> 16);
}
static __device__ __forceinline__ float bf2f(ushort u) {
    union { unsigned int u; float f; } c; c.u = (unsigned int)u << 16; return c.f;
}

// Raw workgroup barrier: drain LDS ops only (NOT vmcnt) — keeps global-load
// prefetch in flight across the barrier (T3/T4; __syncthreads would vmcnt(0)).
static __device__ __forceinline__ void bar_lgkm() {
    asm volatile("s_waitcnt lgkmcnt(0)" ::: "memory");
    __builtin_amdgcn_s_barrier();
    __builtin_amdgcn_sched_barrier(0);
}

// -------- K0: zero out (3 float4/thread) + LayerNorm of 128 cls rows --------
__global__ __launch_bounds__(256) void k_lnq(const float* __restrict__ x,
                                             const float* __restrict__ gamma,
                                             const float* __restrict__ beta,
                                             ushort* __restrict__ qn,
                                             float* __restrict__ out) {
    int zi = blockIdx.x * 256 + threadIdx.x;   // 0..8191
    float4 z = {0.f, 0.f, 0.f, 0.f};
    ((float4*)out)[zi]         = z;
    ((float4*)out)[zi + 8192]  = z;
    ((float4*)out)[zi + 16384] = z;

    int row  = (blockIdx.x << 2) + (threadIdx.x >> 6);   // 0..127
    int lane = threadIdx.x & 63;
    const float4* xr = (const float4*)(x + (size_t)row * DD);
    float4 v[3];
    float s = 0.f, ss = 0.f;
#pragma unroll
    for (int j = 0; j < 3; ++j) {
        v[j] = xr[lane + 64 * j];
        s  += v[j].x + v[j].y + v[j].z + v[j].w;
        ss = fmaf(v[j].x, v[j].x, ss); ss = fmaf(v[j].y, v[j].y, ss);
        ss = fmaf(v[j].z, v[j].z, ss); ss = fmaf(v[j].w, v[j].w, ss);
    }
#pragma unroll
    for (int o = 32; o > 0; o >>= 1) { s += __shfl_xor(s, o); ss += __shfl_xor(ss, o); }
    float mu  = s * (1.f / DD);
    float var = fmaf(ss, 1.f / DD, -mu * mu);
    float rs  = rsqrtf(var + 1e-5f);
    const float4* g4 = (const float4*)gamma;
    const float4* b4 = (const float4*)beta;
    ushort4* outr = (ushort4*)(qn + (size_t)row * DD);
#pragma unroll
    for (int j = 0; j < 3; ++j) {
        int i4 = lane + 64 * j;
        float4 g = g4[i4], b = b4[i4];
        ushort4 o4;
        o4.x = f2bf((v[j].x - mu) * rs * g.x + b.x);
        o4.y = f2bf((v[j].y - mu) * rs * g.y + b.y);
        o4.z = f2bf((v[j].z - mu) * rs * g.z + b.z);
        o4.w = f2bf((v[j].w - mu) * rs * g.w + b.w);
        outr[i4] = o4;
    }
}

// ---- K1: one block per (b, sl). 2 p per block, fused LN + mm1 + band-sigmoid
//      + mm2 with register accumulation. Raw lgkm-only barriers keep the p1
//      register prefetch in flight across the whole p0 compute phase. ----
template<bool USE_PART>
__global__ __launch_bounds__(256, 3) void k_attn(const float* __restrict__ x,
                                                 const float* __restrict__ gamma,
                                                 const float* __restrict__ beta,
                                                 const ushort* __restrict__ qn,
                                                 ushort* __restrict__ part,
                                                 float* __restrict__ out) {
    __shared__ ushort Vl[16 * VS];      // 24832 B, row stride 776
    __shared__ float  Sl[4][TT][17];    // 4352 B, padded
    __shared__ ushort Wl[TT][TT];       // 512 B, row-major [t][r]

    int gid = blockIdx.x;
    int b = gid & 7, sl = gid >> 3;     // sl = 0..97
    int w = threadIdx.x >> 6, l = threadIdx.x & 63;
    int l15 = l & 15, lh = l >> 4;
    int r = w * 4 + lh, j16 = l15;

    // q A-frags for mm1 K-slice [w*192, w*192+192)
    const ushort* qrow = qn + (size_t)(b * TT + l15) * DD + w * 192 + lh * 8;
    short8 qf[6];
#pragma unroll
    for (int s = 0; s < 6; ++s) qf[s] = *(const short8*)(qrow + s * 32);

    f32x4 acc[12];
#pragma unroll
    for (int i = 0; i < 12; ++i) acc[i] = (f32x4){0.f, 0.f, 0.f, 0.f};

    const float4* g4 = (const float4*)gamma;
    const float4* b4 = (const float4*)beta;
    float4 c[12];

#define GLOADP(P)                                                                 \
    {                                                                             \
        const float* vrow = x + ((size_t)(1 + (P)) * NN + b * TT + r) * DD;       \
        _Pragma("unroll")                                                         \
        for (int k = 0; k < 12; ++k) c[k] = *(const float4*)(vrow + (j16 + 16 * k) * 4); \
    }

#define LNPACK()                                                                  \
    {                                                                             \
        float s1 = 0.f, s2 = 0.f;                                                 \
        _Pragma("unroll")                                                         \
        for (int k = 0; k < 12; ++k) {                                            \
            float4 v = c[k];                                                      \
            s1 += v.x + v.y + v.z + v.w;                                          \
            s2 = fmaf(v.x, v.x, s2); s2 = fmaf(v.y, v.y, s2);                     \
            s2 = fmaf(v.z, v.z, s2); s2 = fmaf(v.w, v.w, s2);                     \
        }                                                                         \
        _Pragma("unroll")                                                         \
        for (int o = 1; o < 16; o <<= 1) {                                        \
            s1 += __shfl_xor(s1, o); s2 += __shfl_xor(s2, o);                     \
        }                                                                         \
        float mu  = s1 * (1.f / DD);                                              \
        float var = fmaf(s2, 1.f / DD, -mu * mu);                                 \
        float rs  = rsqrtf(var + 1e-5f);                                          \
        _Pragma("unroll")                                                         \
        for (int k = 0; k < 12; ++k) {                                            \
            int c4 = j16 + 16 * k;                                                \
            float4 g = g4[c4], e = b4[c4];                                        \
            float4 v = c[k];                                                      \
            ushort4 ut;                                                           \
            ut.x = f2bf((v.x - mu) * rs * g.x + e.x);                             \
            ut.y = f2bf((v.y - mu) * rs * g.y + e.y);                             \
            ut.z = f2bf((v.z - mu) * rs * g.z + e.z);                             \
            ut.w = f2bf((v.w - mu) * rs * g.w + e.w);                             \
            *(ushort4*)&Vl[r * VS + c4 * 4] = ut;                                 \
        }                                                                         \
    }

#define MM1W()                                                                    \
    {                                                                             \
        f32x4 sacc = (f32x4){0.f, 0.f, 0.f, 0.f};                                 \
        _Pragma("unroll")                                                         \
        for (int s = 0; s < 6; ++s) {                                             \
            int k0 = w * 192 + s * 32 + lh * 8;                                   \
            short8 bfr = *(const short8*)&Vl[l15 * VS + k0];                      \
            sacc = __builtin_amdgcn_mfma_f32_16x16x32_bf16(qf[s], bfr, sacc, 0, 0, 0); \
        }                                                                         \
        _Pragma("unroll")                                                         \
        for (int q = 0; q < 4; ++q) Sl[w][lh * 4 + q][l15] = sacc[q];             \
        bar_lgkm();                                                               \
        {                                                                         \
            int t  = threadIdx.x >> 4, rr = threadIdx.x & 15;                     \
            float s = Sl[0][t][rr] + Sl[1][t][rr] + Sl[2][t][rr] + Sl[3][t][rr];  \
            int dlt = rr - t;                                                     \
            float wv = (dlt <= 2 && dlt >= -2)                                    \
                         ? (1.f / (1.f + __expf(-s * SCL)) - 0.5f) : 0.f;         \
            Wl[t][rr] = f2bf(wv);                                                 \
        }                                                                         \
        bar_lgkm();                                                               \
    }

#define MM2()                                                                     \
    {                                                                             \
        short8 wfrag = (short8){0, 0, 0, 0, 0, 0, 0, 0};                          \
        if (lh < 2) wfrag = *(const short8*)&Wl[l15][lh * 8];                     \
        _Pragma("unroll")                                                         \
        for (int i = 0; i < 12; ++i) {                                            \
            int d0 = w * 192 + i * 16;                                            \
            union { ushort sv[8]; short8 v; } u;                                  \
            u.v = (short8){0, 0, 0, 0, 0, 0, 0, 0};                               \
            if (lh < 2) {                                                         \
                _Pragma("unroll")                                                 \
                for (int j = 0; j < 8; ++j)                                       \
                    u.sv[j] = Vl[(lh * 8 + j) * VS + d0 + l15];                   \
            }                                                                     \
            acc[i] = __builtin_amdgcn_mfma_f32_16x16x32_bf16(wfrag, u.v, acc[i], 0, 0, 0); \
        }                                                                         \
    }

    GLOADP(sl * 2);
    LNPACK();
    bar_lgkm();
    GLOADP(sl * 2 + 1);   // prefetch p1; stays in flight across mm1/W/mm2 now
    MM1W();
    MM2();
    bar_lgkm();           // Vl free (mm2 reads consumed before this barrier)
    LNPACK();
    bar_lgkm();
    MM1W();
    MM2();

#undef GLOADP
#undef LNPACK
#undef MM1W
#undef MM2

    // ---- epilogue ----
    if (USE_PART) {
        ushort* myp = part + (size_t)(sl * 8 + b) * (TT * DD);
#pragma unroll
        for (int i = 0; i < 12; ++i) {
            ushort4 pk;
            pk.x = f2bf(acc[i][0]); pk.y = f2bf(acc[i][1]);
            pk.z = f2bf(acc[i][2]); pk.w = f2bf(acc[i][3]);
            *(ushort4*)&myp[((w * 12 + i) * 64 + l) * 4] = pk;
        }
    } else {
#pragma unroll
        for (int i = 0; i < 12; ++i) {
            int d0 = w * 192 + i * 16;
#pragma unroll
            for (int q = 0; q < 4; ++q)
                atomicAdd(out + (size_t)(b * TT + lh * 4 + q) * DD + d0 + l15, acc[i][q]);
        }
    }
}

// ---- K2: reduce 98 fragment-order bf16 partials; 7 slice-chunks x 96 blocks -
__global__ __launch_bounds__(256) void k_reduce(const ushort* __restrict__ part,
                                                float* __restrict__ out) {
    int bid = blockIdx.x;
    int pc  = bid % 7;                       // slice-chunk: 14 slices
    int g   = (bid / 7) * 256 + threadIdx.x; // 0..24575: (b, pos4)
    int b    = g / 3072;
    int pos4 = g - b * 3072;                 // float4-group within slice
    const ushort* src = part + (size_t)b * (TT * DD) + pos4 * 4;

    float s0 = 0.f, s1 = 0.f, s2 = 0.f, s3 = 0.f;
#pragma unroll 2
    for (int s = pc * 14; s < pc * 14 + 14; ++s) {
        union { short4v v; ushort sv[4]; } u;
        u.v = *(const short4v*)(src + (size_t)s * 8 * (TT * DD));
        s0 += bf2f(u.sv[0]); s1 += bf2f(u.sv[1]);
        s2 += bf2f(u.sv[2]); s3 += bf2f(u.sv[3]);
    }
    // decode fragment position -> (t, d)
    int fp    = pos4 * 4;
    int chunk = fp >> 8;           // w*12 + i
    int l     = (fp >> 2) & 63;
    int w     = chunk / 12, i = chunk - w * 12;
    int lh    = l >> 4,   l15 = l & 15;
    int d     = w * 192 + i * 16 + l15;
    float* dst = out + ((size_t)b * TT + lh * 4) * DD + d;
    atomicAdd(dst,          s0);
    atomicAdd(dst + 1 * DD, s1);
    atomicAdd(dst + 2 * DD, s2);
    atomicAdd(dst + 3 * DD, s3);
}

extern "C" void kernel_launch(void* const* d_in, const int* in_sizes, int n_in,
                              void* d_out, int out_size, void* d_ws, size_t ws_size,
                              hipStream_t stream) {
    const float* x     = (const float*)d_in[0];
    const float* gamma = (const float*)d_in[1];
    const float* beta  = (const float*)d_in[2];
    float* out = (float*)d_out;

    const size_t qn_bytes   = (size_t)NN * DD * 2;                  // 196,608
    const size_t part_bytes = (size_t)NSL * 8 * TT * DD * 2;        // 19,267,584
    ushort* qn   = (ushort*)d_ws;
    ushort* part = (ushort*)((char*)d_ws + qn_bytes);
    bool use_part = ws_size >= qn_bytes + part_bytes;

    k_lnq<<<NN / 4, 256, 0, stream>>>(x, gamma, beta, qn, out);
    if (use_part) {
        k_attn<true><<<8 * NSL, 256, 0, stream>>>(x, gamma, beta, qn, part, out);
        k_reduce<<<7 * 96, 256, 0, stream>>>(part, out);
    } else {
        k_attn<false><<<8 * NSL, 256, 0, stream>>>(x, gamma, beta, qn, part, out);
    }
}

// Round 13
// 38.652 us; speedup vs baseline: 2.2697x; 1.0547x over previous
//
#include <hip/hip_runtime.h>

#define NN 128
#define DD 768
#define TT 16
#define PP 196
#define NSL 98                    // slices per b, 2 p each
#define SCL 0.03608439182435161f  // 1/sqrt(768)

typedef short short8 __attribute__((ext_vector_type(8)));
typedef short short4v __attribute__((ext_vector_type(4)));
typedef float f32x4 __attribute__((ext_vector_type(4)));

static __device__ __forceinline__ ushort f2bf(float f) {
    union { float f; unsigned int u; } a; a.f = f;
    unsigned int r = a.u + 0x7fffu + ((a.u >> 16) & 1u);
    return (ushort)(r >> 16);
}
static __device__ __forceinline__ float bf2f(ushort u) {
    union { unsigned int u; float f; } c; c.u = (unsigned int)u << 16; return c.f;
}

// Verified (R4/R5) swizzled LDS index for a 32x768 bf16 tile.
static __device__ __forceinline__ int vidx(int r, int d) {
    return r * DD + ((((d >> 3) ^ (r & 7)) << 3) | (d & 7));
}

// Raw workgroup barrier: drain LDS ops only (NOT vmcnt).
static __device__ __forceinline__ void bar_lgkm() {
    asm volatile("s_waitcnt lgkmcnt(0)" ::: "memory");
    __builtin_amdgcn_s_barrier();
    __builtin_amdgcn_sched_barrier(0);
}

// -------- K0: zero out (3 float4/thread) + LayerNorm of 128 cls rows --------
__global__ __launch_bounds__(256) void k_lnq(const float* __restrict__ x,
                                             const float* __restrict__ gamma,
                                             const float* __restrict__ beta,
                                             ushort* __restrict__ qn,
                                             float* __restrict__ out) {
    int zi = blockIdx.x * 256 + threadIdx.x;   // 0..8191
    float4 z = {0.f, 0.f, 0.f, 0.f};
    ((float4*)out)[zi]         = z;
    ((float4*)out)[zi + 8192]  = z;
    ((float4*)out)[zi + 16384] = z;

    int row  = (blockIdx.x << 2) + (threadIdx.x >> 6);   // 0..127
    int lane = threadIdx.x & 63;
    const float4* xr = (const float4*)(x + (size_t)row * DD);
    float4 v[3];
    float s = 0.f, ss = 0.f;
#pragma unroll
    for (int j = 0; j < 3; ++j) {
        v[j] = xr[lane + 64 * j];
        s  += v[j].x + v[j].y + v[j].z + v[j].w;
        ss = fmaf(v[j].x, v[j].x, ss); ss = fmaf(v[j].y, v[j].y, ss);
        ss = fmaf(v[j].z, v[j].z, ss); ss = fmaf(v[j].w, v[j].w, ss);
    }
#pragma unroll
    for (int o = 32; o > 0; o >>= 1) { s += __shfl_xor(s, o); ss += __shfl_xor(ss, o); }
    float mu  = s * (1.f / DD);
    float var = fmaf(ss, 1.f / DD, -mu * mu);
    float rs  = rsqrtf(var + 1e-5f);
    const float4* g4 = (const float4*)gamma;
    const float4* b4 = (const float4*)beta;
    ushort4* outr = (ushort4*)(qn + (size_t)row * DD);
#pragma unroll
    for (int j = 0; j < 3; ++j) {
        int i4 = lane + 64 * j;
        float4 g = g4[i4], b = b4[i4];
        ushort4 o4;
        o4.x = f2bf((v[j].x - mu) * rs * g.x + b.x);
        o4.y = f2bf((v[j].y - mu) * rs * g.y + b.y);
        o4.z = f2bf((v[j].z - mu) * rs * g.z + b.z);
        o4.w = f2bf((v[j].w - mu) * rs * g.w + b.w);
        outr[i4] = o4;
    }
}

// ---- K1: one block per (b, sl), 8 waves, ONE 32-row pass:
//      stage(LN fused) -> bar -> mm1 (K/8 per wave, 2 col-groups) -> bar ->
//      W over 32 cols -> bar -> mm2 (K=32 all-real, 96-d slice per wave). ----
template<bool USE_PART>
__global__ __launch_bounds__(512, 4) void k_attn(const float* __restrict__ x,
                                                 const float* __restrict__ gamma,
                                                 const float* __restrict__ beta,
                                                 const ushort* __restrict__ qn,
                                                 ushort* __restrict__ part,
                                                 float* __restrict__ out) {
    __shared__ ushort Vl[32 * DD];      // 49152 B, swizzled
    __shared__ float  Sl[8][TT][33];    // 16896 B
    __shared__ ushort Wl[TT][32];       // 1024 B

    int gid = blockIdx.x;
    int b = gid & 7, sl = gid >> 3;     // sl = 0..97
    int w = threadIdx.x >> 6, l = threadIdx.x & 63;
    int l15 = l & 15, lh = l >> 4;

    // ---- stage: thread = (row r = tid>>4, j = tid&15); LN fused, pack bf16 --
    {
        int r = threadIdx.x >> 4, j = threadIdx.x & 15;
        const float* vrow =
            x + ((size_t)(1 + sl * 2 + (r >> 4)) * NN + b * TT + (r & 15)) * DD;
        float4 c[12];
#pragma unroll
        for (int k = 0; k < 12; ++k) c[k] = *(const float4*)(vrow + (j + 16 * k) * 4);
        float s1 = 0.f, s2 = 0.f;
#pragma unroll
        for (int k = 0; k < 12; ++k) {
            float4 v = c[k];
            s1 += v.x + v.y + v.z + v.w;
            s2 = fmaf(v.x, v.x, s2); s2 = fmaf(v.y, v.y, s2);
            s2 = fmaf(v.z, v.z, s2); s2 = fmaf(v.w, v.w, s2);
        }
#pragma unroll
        for (int o = 1; o < 16; o <<= 1) { s1 += __shfl_xor(s1, o); s2 += __shfl_xor(s2, o); }
        float mu  = s1 * (1.f / DD);
        float var = fmaf(s2, 1.f / DD, -mu * mu);
        float rs  = rsqrtf(var + 1e-5f);
        const float4* g4 = (const float4*)gamma;
        const float4* b4 = (const float4*)beta;
#pragma unroll
        for (int k = 0; k < 12; ++k) {
            int c4 = j + 16 * k;
            float4 g = g4[c4], e = b4[c4];
            float4 v = c[k];
            ushort4 ut;
            ut.x = f2bf((v.x - mu) * rs * g.x + e.x);
            ut.y = f2bf((v.y - mu) * rs * g.y + e.y);
            ut.z = f2bf((v.z - mu) * rs * g.z + e.z);
            ut.w = f2bf((v.w - mu) * rs * g.w + e.w);
            *(ushort4*)&Vl[vidx(r, c4 * 4)] = ut;
        }
    }
    bar_lgkm();

    // ---- mm1: wave w covers K-slice [w*96, w*96+96), both 16-col groups ----
    {
        const ushort* qrow = qn + (size_t)(b * TT + l15) * DD + w * 96 + lh * 8;
        short8 qf[3];
#pragma unroll
        for (int s = 0; s < 3; ++s) qf[s] = *(const short8*)(qrow + s * 32);
#pragma unroll
        for (int cg = 0; cg < 2; ++cg) {
            f32x4 sacc = (f32x4){0.f, 0.f, 0.f, 0.f};
            int vr = cg * 16 + l15;
#pragma unroll
            for (int s = 0; s < 3; ++s) {
                int k0 = w * 96 + s * 32 + lh * 8;
                short8 bfr = *(const short8*)&Vl[vidx(vr, k0)];
                sacc = __builtin_amdgcn_mfma_f32_16x16x32_bf16(qf[s], bfr, sacc, 0, 0, 0);
            }
#pragma unroll
            for (int q = 0; q < 4; ++q) Sl[w][lh * 4 + q][cg * 16 + l15] = sacc[q];
        }
    }
    bar_lgkm();

    // ---- W: 512 threads = (t, rr in 0..31): sum 8 K-slices, band sigmoid ----
    {
        int t  = threadIdx.x >> 5, rr = threadIdx.x & 31;
        float s = 0.f;
#pragma unroll
        for (int k = 0; k < 8; ++k) s += Sl[k][t][rr];
        int m = rr & 15;
        int dlt = m - t;
        float wv = (dlt <= 2 && dlt >= -2)
                     ? (1.f / (1.f + __expf(-s * SCL)) - 0.5f) : 0.f;
        Wl[t][rr] = f2bf(wv);
    }
    bar_lgkm();

    // ---- mm2: K=32 (all real rows), wave owns d-slice [w*96, w*96+96) ----
    f32x4 acc[6];
    {
        short8 wfrag = *(const short8*)&Wl[l15][lh * 8];
#pragma unroll
        for (int i = 0; i < 6; ++i) {
            int d0 = w * 96 + i * 16;
            union { ushort sv[8]; short8 v; } u;
#pragma unroll
            for (int j = 0; j < 8; ++j)
                u.sv[j] = Vl[vidx(lh * 8 + j, d0 + l15)];
            acc[i] = __builtin_amdgcn_mfma_f32_16x16x32_bf16(
                wfrag, u.v, (f32x4){0.f, 0.f, 0.f, 0.f}, 0, 0, 0);
        }
    }

    // ---- epilogue: fragment-order coalesced partial store ----
    if (USE_PART) {
        ushort* myp = part + (size_t)(sl * 8 + b) * (TT * DD);
#pragma unroll
        for (int i = 0; i < 6; ++i) {
            ushort4 pk;
            pk.x = f2bf(acc[i][0]); pk.y = f2bf(acc[i][1]);
            pk.z = f2bf(acc[i][2]); pk.w = f2bf(acc[i][3]);
            *(ushort4*)&myp[((w * 6 + i) * 64 + l) * 4] = pk;
        }
    } else {
#pragma unroll
        for (int i = 0; i < 6; ++i) {
            int d0 = w * 96 + i * 16;
#pragma unroll
            for (int q = 0; q < 4; ++q)
                atomicAdd(out + (size_t)(b * TT + lh * 4 + q) * DD + d0 + l15, acc[i][q]);
        }
    }
}

// ---- K2: reduce 98 fragment-order bf16 partials; 7 slice-chunks x 96 blocks -
__global__ __launch_bounds__(256) void k_reduce(const ushort* __restrict__ part,
                                                float* __restrict__ out) {
    int bid = blockIdx.x;
    int pc  = bid % 7;                       // slice-chunk: 14 slices
    int g   = (bid / 7) * 256 + threadIdx.x; // 0..24575: (b, pos4)
    int b    = g / 3072;
    int pos4 = g - b * 3072;                 // float4-group within slice
    const ushort* src = part + (size_t)b * (TT * DD) + pos4 * 4;

    float s0 = 0.f, s1 = 0.f, s2 = 0.f, s3 = 0.f;
#pragma unroll 2
    for (int s = pc * 14; s < pc * 14 + 14; ++s) {
        union { short4v v; ushort sv[4]; } u;
        u.v = *(const short4v*)(src + (size_t)s * 8 * (TT * DD));
        s0 += bf2f(u.sv[0]); s1 += bf2f(u.sv[1]);
        s2 += bf2f(u.sv[2]); s3 += bf2f(u.sv[3]);
    }
    // decode fragment position -> (t, d): chunk = w*6+i
    int fp    = pos4 * 4;
    int chunk = fp >> 8;           // 0..47
    int l     = (fp >> 2) & 63;
    int w     = chunk / 6, i = chunk - w * 6;
    int lh    = l >> 4,   l15 = l & 15;
    int d     = w * 96 + i * 16 + l15;
    float* dst = out + ((size_t)b * TT + lh * 4) * DD + d;
    atomicAdd(dst,          s0);
    atomicAdd(dst + 1 * DD, s1);
    atomicAdd(dst + 2 * DD, s2);
    atomicAdd(dst + 3 * DD, s3);
}

extern "C" void kernel_launch(void* const* d_in, const int* in_sizes, int n_in,
                              void* d_out, int out_size, void* d_ws, size_t ws_size,
                              hipStream_t stream) {
    const float* x     = (const float*)d_in[0];
    const float* gamma = (const float*)d_in[1];
    const float* beta  = (const float*)d_in[2];
    float* out = (float*)d_out;

    const size_t qn_bytes   = (size_t)NN * DD * 2;                  // 196,608
    const size_t part_bytes = (size_t)NSL * 8 * TT * DD * 2;        // 19,267,584
    ushort* qn   = (ushort*)d_ws;
    ushort* part = (ushort*)((char*)d_ws + qn_bytes);
    bool use_part = ws_size >= qn_bytes + part_bytes;

    k_lnq<<<NN / 4, 256, 0, stream>>>(x, gamma, beta, qn, out);
    if (use_part) {
        k_attn<true><<<8 * NSL, 512, 0, stream>>>(x, gamma, beta, qn, part, out);
        k_reduce<<<7 * 96, 256, 0, stream>>>(part, out);
    } else {
        k_attn<false><<<8 * NSL, 512, 0, stream>>>(x, gamma, beta, qn, part, out);
    }
}